// Round 7
// baseline (468.191 us; speedup 1.0000x reference)
//
#include <hip/hip_runtime.h>
#include <hip/hip_bf16.h>

#define NEG_SLOPE 0.2f
typedef unsigned int uint32;

#define BSHIFT 9
#define BSIZE 512          // nodes per bucket
#define MAXB 256           // max buckets (N < 131072)
#define PCHUNK 4096        // edges per partition/hist block

typedef __attribute__((ext_vector_type(8))) __bf16 bf16x8;
typedef __attribute__((ext_vector_type(4))) float f32x4;

__device__ __forceinline__ float selu_f(float x) {
    const float a = 1.6732632423543772f, s = 1.0507009873554805f;
    return x > 0.0f ? s * x : s * a * (__expf(x) - 1.0f);
}

__device__ __forceinline__ unsigned short f2bf(float x) {
    uint32 u = __float_as_uint(x);
    uint32 r = (u + 0x7fff + ((u >> 16) & 1)) >> 16;   // RNE
    return (unsigned short)r;
}
__device__ __forceinline__ float bf_lo(uint32 g) { return __uint_as_float(g << 16); }
__device__ __forceinline__ float bf_hi(uint32 g) { return __uint_as_float(g & 0xffff0000u); }

// ---- fused prep: repack W (blocks 0,1) + graph_bounds + bucket_hist ------
__global__ __launch_bounds__(256) void prep(const float* __restrict__ W1,
                                            const float* __restrict__ W2,
                                            unsigned short* __restrict__ Wb,
                                            const int* __restrict__ batch,
                                            int* __restrict__ gstart,
                                            const int* __restrict__ ei,
                                            int* __restrict__ gpart,
                                            int N, int G, int E, int TOT, int GB) {
    __shared__ int lh[MAXB];
    int b = blockIdx.x, t = threadIdx.x;
    if (b < 2) {
        // repack W[128][128] fp32 -> B-fragment-ordered bf16 hi/lo
        const float* W = b ? W2 : W1;
        unsigned short* oh = Wb + (size_t)b * 32768;
        unsigned short* ol = oh + 16384;
        for (int d = t; d < 16384; d += 256) {
            int j = d & 7, nn = (d >> 3) & 127, g = d >> 10;
            float v = W[(g * 8 + j) * 128 + nn];
            uint32 hu = f2bf(v);
            float hv = __uint_as_float(hu << 16);
            oh[d] = (unsigned short)hu;
            ol[d] = f2bf(v - hv);
        }
    } else if (b < 2 + GB) {
        // graph bounds from sorted batch
        int i = (b - 2) * 256 + t;
        if (i < N) {
            int bb = batch[i];
            int bp = (i == 0) ? -1 : batch[i - 1];
            for (int q = bp + 1; q <= bb; ++q) gstart[q] = i;
            if (i == N - 1)
                for (int q = bb + 1; q <= G; ++q) gstart[q] = N;
        }
    } else {
        // per-chunk bucket histogram -> plain partial writes (no atomics/memset)
        int hb_ = b - 2 - GB;
        lh[t] = 0;
        __syncthreads();
        int eb = hb_ * PCHUNK;
        #pragma unroll
        for (int k = 0; k < PCHUNK / 256; ++k) {
            int e = eb + k * 256 + t;
            if (e < TOT) {
                int d = (e < E) ? ei[E + e] : e - E;
                atomicAdd(&lh[d >> BSHIFT], 1);
            }
        }
        __syncthreads();
        gpart[hb_ * MAXB + t] = lh[t];
    }
}

// ---- sum partials + exclusive scan of bucket counts ----------------------
__global__ __launch_bounds__(256) void bucket_scan2(const int* __restrict__ gpart,
                                                    int nparts,
                                                    int* __restrict__ bstart,
                                                    int* __restrict__ gcursor,
                                                    int NB, int TOT) {
    __shared__ int sh[256];
    int t = threadIdx.x;
    int v = 0;
    for (int p = 0; p < nparts; ++p) v += gpart[p * MAXB + t];
    sh[t] = v;
    __syncthreads();
    for (int off = 1; off < 256; off <<= 1) {
        int add = (t >= off) ? sh[t - off] : 0;
        __syncthreads();
        sh[t] += add;
        __syncthreads();
    }
    int ex = sh[t] - v;
    if (t < NB) { bstart[t] = ex; gcursor[t] = ex; }
    if (t == 0) bstart[NB] = TOT;
}

// ------------- partition edges into buckets (LDS counting sort) -----------
__global__ __launch_bounds__(256) void partition_edges(const int* __restrict__ ei,
                                                       int* __restrict__ gcursor,
                                                       uint32* __restrict__ tmp,
                                                       int E, int TOT) {
    __shared__ int lcnt[MAXB];
    __shared__ int lstart[MAXB];
    __shared__ int lcur[MAXB];
    __shared__ int gbase[MAXB];
    __shared__ uint32 staged[PCHUNK];
    __shared__ unsigned char bslot[PCHUNK];
    int t = threadIdx.x;
    int eb = blockIdx.x * PCHUNK;
    int sreg[16], dreg[16];
    #pragma unroll
    for (int k = 0; k < 16; ++k) {
        int e = eb + k * 256 + t;
        if (e < TOT) {
            if (e < E) { sreg[k] = ei[e]; dreg[k] = ei[E + e]; }
            else       { sreg[k] = dreg[k] = e - E; }
        } else dreg[k] = -1;
    }
    lcnt[t] = 0;
    __syncthreads();
    #pragma unroll
    for (int k = 0; k < 16; ++k)
        if (dreg[k] >= 0) atomicAdd(&lcnt[dreg[k] >> BSHIFT], 1);
    __syncthreads();
    int v = lcnt[t];
    lstart[t] = v;
    __syncthreads();
    for (int off = 1; off < 256; off <<= 1) {
        int add = (t >= off) ? lstart[t - off] : 0;
        __syncthreads();
        lstart[t] += add;
        __syncthreads();
    }
    int ex = lstart[t] - v;
    __syncthreads();
    lstart[t] = ex;
    lcur[t] = ex;
    if (v > 0) gbase[t] = atomicAdd(&gcursor[t], v);
    __syncthreads();
    #pragma unroll
    for (int k = 0; k < 16; ++k) {
        int d = dreg[k];
        if (d >= 0) {
            int b = d >> BSHIFT;
            int p = atomicAdd(&lcur[b], 1);
            staged[p] = ((uint32)(d & (BSIZE - 1)) << 17) | (uint32)sreg[k];
            bslot[p] = (unsigned char)b;
        }
    }
    __syncthreads();
    int nvalid = TOT - eb; if (nvalid > PCHUNK) nvalid = PCHUNK;
    for (int i = t; i < nvalid; i += 256) {
        int b = bslot[i];
        tmp[gbase[b] + (i - lstart[b])] = staged[i];
    }
}

// ------------- per-bucket: per-node scan -> rowptr + col scatter ----------
__global__ __launch_bounds__(256) void bucket_build(const uint32* __restrict__ tmp,
                                                    const int* __restrict__ bstart,
                                                    int* __restrict__ rowptr,
                                                    int* __restrict__ col,
                                                    int N, int TOT, int NB) {
    __shared__ int cnt[BSIZE];
    __shared__ int sums[256];
    int b = blockIdx.x, t = threadIdx.x;
    int lo = b << BSHIFT;
    int nn = N - lo; if (nn > BSIZE) nn = BSIZE;
    cnt[t] = 0; cnt[t + 256] = 0;
    __syncthreads();
    int ebeg = bstart[b], eend = bstart[b + 1];
    for (int i = ebeg + t; i < eend; i += 256)
        atomicAdd(&cnt[tmp[i] >> 17], 1);
    __syncthreads();
    int c0 = cnt[2 * t], c1 = cnt[2 * t + 1];
    int s2 = c0 + c1;
    sums[t] = s2;
    __syncthreads();
    for (int off = 1; off < 256; off <<= 1) {
        int add = (t >= off) ? sums[t - off] : 0;
        __syncthreads();
        sums[t] += add;
        __syncthreads();
    }
    int ex = sums[t] - s2;
    int st0 = ebeg + ex, st1 = st0 + c0;
    if (2 * t < nn)     rowptr[lo + 2 * t] = st0;
    if (2 * t + 1 < nn) rowptr[lo + 2 * t + 1] = st1;
    cnt[2 * t] = st0; cnt[2 * t + 1] = st1;
    __syncthreads();
    for (int i = ebeg + t; i < eend; i += 256) {
        uint32 u = tmp[i];
        int p = atomicAdd(&cnt[u >> 17], 1);
        col[p] = (int)(u & 0x1FFFFu);
    }
    if (b == NB - 1 && t == 0) rowptr[N] = TOT;
}

// ---- shared MFMA core: A(bf16) x (B_hi + B_lo), 128 rows/block -----------
__device__ __forceinline__ void gemm_core(const bf16x8 ah[2][4],
                                          const __bf16* Wl,
                                          const float* a_src, const float* a_dst,
                                          uint32* hb, float* as_, float* ad_,
                                          int rbase, int n, int col16, int quad) {
    f32x4 acc[2][8];
    #pragma unroll
    for (int mt = 0; mt < 2; ++mt)
        #pragma unroll
        for (int t = 0; t < 8; ++t) acc[mt][t] = (f32x4)(0.0f);

    #pragma unroll
    for (int c = 0; c < 4; ++c) {
        #pragma unroll
        for (int t = 0; t < 8; ++t) {
            int off = (((c * 4 + quad) * 128) + t * 16 + col16) * 8;
            bf16x8 bh = *(const bf16x8*)&Wl[off];
            bf16x8 bl = *(const bf16x8*)&Wl[16384 + off];
            #pragma unroll
            for (int mt = 0; mt < 2; ++mt) {
                acc[mt][t] = __builtin_amdgcn_mfma_f32_16x16x32_bf16(ah[mt][c], bh, acc[mt][t], 0, 0, 0);
                acc[mt][t] = __builtin_amdgcn_mfma_f32_16x16x32_bf16(ah[mt][c], bl, acc[mt][t], 0, 0, 0);
            }
        }
    }
    float asv[8], adv[8];
    #pragma unroll
    for (int t = 0; t < 8; ++t) { asv[t] = a_src[t * 16 + col16]; adv[t] = a_dst[t * 16 + col16]; }
    #pragma unroll
    for (int mt = 0; mt < 2; ++mt) {
        #pragma unroll
        for (int reg = 0; reg < 4; ++reg) {
            float s = 0.0f, d = 0.0f;
            #pragma unroll
            for (int t = 0; t < 8; ++t) {
                float v = acc[mt][t][reg];
                s += v * asv[t]; d += v * adv[t];
            }
            #pragma unroll
            for (int off = 1; off < 16; off <<= 1) {
                s += __shfl_xor(s, off);
                d += __shfl_xor(d, off);
            }
            int r = rbase + mt * 16 + quad * 4 + reg;
            if (col16 == 0 && r < n) { as_[r] = s; ad_[r] = d; }
        }
    }
    #pragma unroll
    for (int mt = 0; mt < 2; ++mt)
    #pragma unroll
    for (int t = 0; t < 8; ++t)
    #pragma unroll
    for (int reg = 0; reg < 4; ++reg) {
        float v = acc[mt][t][reg];
        float p = __shfl_xor(v, 1);
        int r = rbase + mt * 16 + quad * 4 + reg;
        if (!(col16 & 1) && r < n) {
            uint32 pk = (uint32)f2bf(v) | ((uint32)f2bf(p) << 16);
            hb[(size_t)r * 64 + t * 8 + (col16 >> 1)] = pk;
        }
    }
}

__global__ __launch_bounds__(256) void gemm_mfma_f32(const float* __restrict__ X,
                                                     const unsigned short* __restrict__ Wbh,
                                                     const float* __restrict__ a_src,
                                                     const float* __restrict__ a_dst,
                                                     uint32* __restrict__ hb,
                                                     float* __restrict__ as_,
                                                     float* __restrict__ ad_, int n) {
    __shared__ __bf16 Wl[32768];   // 64 KB hi+lo
    const int tid = threadIdx.x;
    {
        const uint4* sw = (const uint4*)Wbh;
        uint4* dw = (uint4*)Wl;
        for (int i = tid; i < 4096; i += 256) dw[i] = sw[i];
    }
    const int lane = tid & 63, wid = tid >> 6;
    const int col16 = lane & 15, quad = lane >> 4;
    const int rbase = blockIdx.x * 128 + wid * 32;
    bf16x8 ah[2][4];
    #pragma unroll
    for (int mt = 0; mt < 2; ++mt) {
        int r = rbase + mt * 16 + col16;
        bool ok = (r < n);
        const float* xp = X + (size_t)r * 128;
        #pragma unroll
        for (int c = 0; c < 4; ++c) {
            int k0 = c * 32 + quad * 8;
            float4 x0 = ok ? *(const float4*)(xp + k0)     : make_float4(0.f,0.f,0.f,0.f);
            float4 x1 = ok ? *(const float4*)(xp + k0 + 4) : make_float4(0.f,0.f,0.f,0.f);
            float xs[8] = {x0.x,x0.y,x0.z,x0.w,x1.x,x1.y,x1.z,x1.w};
            #pragma unroll
            for (int j = 0; j < 8; ++j) ah[mt][c][j] = (__bf16)xs[j];
        }
    }
    __syncthreads();
    gemm_core(ah, Wl, a_src, a_dst, hb, as_, ad_, rbase, n, col16, quad);
}

__global__ __launch_bounds__(256) void gemm_mfma_bf16(const __bf16* __restrict__ X,
                                                      const unsigned short* __restrict__ Wbh,
                                                      const float* __restrict__ a_src,
                                                      const float* __restrict__ a_dst,
                                                      uint32* __restrict__ hb,
                                                      float* __restrict__ as_,
                                                      float* __restrict__ ad_, int n) {
    __shared__ __bf16 Wl[32768];
    const int tid = threadIdx.x;
    {
        const uint4* sw = (const uint4*)Wbh;
        uint4* dw = (uint4*)Wl;
        for (int i = tid; i < 4096; i += 256) dw[i] = sw[i];
    }
    const int lane = tid & 63, wid = tid >> 6;
    const int col16 = lane & 15, quad = lane >> 4;
    const int rbase = blockIdx.x * 128 + wid * 32;
    bf16x8 ah[2][4];
    const bf16x8 zz = (bf16x8)((__bf16)0.0f);
    #pragma unroll
    for (int mt = 0; mt < 2; ++mt) {
        int r = rbase + mt * 16 + col16;
        bool ok = (r < n);
        const __bf16* xp = X + (size_t)r * 128;
        #pragma unroll
        for (int c = 0; c < 4; ++c)
            ah[mt][c] = ok ? *(const bf16x8*)(xp + c * 32 + quad * 8) : zz;
    }
    __syncthreads();
    gemm_core(ah, Wl, a_src, a_dst, hb, as_, ad_, rbase, n, col16, quad);
}

// ---- fused GAT v4: 1 node/wave; 4 edge-groups x 16 lanes x uint4 gathers --
// no LDS: weight/src broadcast from phase-1 registers via shfl.
__global__ __launch_bounds__(256) void gat_csr4(const int* __restrict__ rowptr,
                                                const int* __restrict__ col,
                                                const uint4* __restrict__ hb4,
                                                const float* __restrict__ as_,
                                                const float* __restrict__ ad_,
                                                const float* __restrict__ bias,
                                                uint4* __restrict__ outb4, int n) {
    const int wid = threadIdx.x >> 6;
    const int lane = threadIdx.x & 63;
    const int grp = lane >> 4, fl = lane & 15;
    const int node = blockIdx.x * 4 + wid;
    if (node >= n) return;
    const int beg = rowptr[node], end = rowptr[node + 1];
    const float add = ad_[node];
    const int deg = end - beg;
    float m = -INFINITY, s = 0.0f;
    float a0=0.f,a1=0.f,a2=0.f,a3=0.f,a4=0.f,a5=0.f,a6=0.f,a7=0.f;
    for (int cb = 0; cb < deg; cb += 64) {
        int j = beg + cb + lane;
        bool eok = (j < end);
        int srcn = eok ? col[j] : 0;
        float v = eok ? (as_[srcn] + add) : -INFINITY;
        v = (v > 0.0f) ? v : NEG_SLOPE * v;
        float cm = v;
        #pragma unroll
        for (int off = 32; off > 0; off >>= 1) cm = fmaxf(cm, __shfl_xor(cm, off));
        float nm = fmaxf(m, cm);
        float w = eok ? __expf(v - nm) : 0.0f;
        float ws = w;
        #pragma unroll
        for (int off = 32; off > 0; off >>= 1) ws += __shfl_xor(ws, off);
        float scale = (m == -INFINITY) ? 0.0f : __expf(m - nm);
        s = s * scale + ws;
        a0*=scale; a1*=scale; a2*=scale; a3*=scale;
        a4*=scale; a5*=scale; a6*=scale; a7*=scale;
        int cnt = end - beg - cb; cnt = (cnt > 64) ? 64 : cnt;
        // 4 groups x 2-deep unroll: 8 edges per iteration, 16 B/lane gathers
        for (int tt = 0; tt < cnt; tt += 8) {
            int e0 = tt + grp, e1 = tt + 4 + grp;
            float w0 = __shfl(w, e0);
            int   s0 = __shfl(srcn, e0);
            float w1 = __shfl(w, e1);
            int   s1 = __shfl(srcn, e1);
            bool v0 = e0 < cnt, v1 = e1 < cnt;
            uint4 g0, g1;
            if (v0) g0 = hb4[(uint32)s0 * 16u + fl];
            if (v1) g1 = hb4[(uint32)s1 * 16u + fl];
            if (v0) {
                a0 += w0 * bf_lo(g0.x); a1 += w0 * bf_hi(g0.x);
                a2 += w0 * bf_lo(g0.y); a3 += w0 * bf_hi(g0.y);
                a4 += w0 * bf_lo(g0.z); a5 += w0 * bf_hi(g0.z);
                a6 += w0 * bf_lo(g0.w); a7 += w0 * bf_hi(g0.w);
            }
            if (v1) {
                a0 += w1 * bf_lo(g1.x); a1 += w1 * bf_hi(g1.x);
                a2 += w1 * bf_lo(g1.y); a3 += w1 * bf_hi(g1.y);
                a4 += w1 * bf_lo(g1.z); a5 += w1 * bf_hi(g1.z);
                a6 += w1 * bf_lo(g1.w); a7 += w1 * bf_hi(g1.w);
            }
        }
        m = nm;
    }
    // reduce across the 4 groups (lanes with same fl)
    #pragma unroll
    for (int off = 16; off < 64; off <<= 1) {
        a0 += __shfl_xor(a0, off); a1 += __shfl_xor(a1, off);
        a2 += __shfl_xor(a2, off); a3 += __shfl_xor(a3, off);
        a4 += __shfl_xor(a4, off); a5 += __shfl_xor(a5, off);
        a6 += __shfl_xor(a6, off); a7 += __shfl_xor(a7, off);
    }
    if (grp == 0) {
        float inv = 1.0f / s;
        float4 b0 = *(const float4*)&bias[fl * 8];
        float4 b1 = *(const float4*)&bias[fl * 8 + 4];
        float r0 = selu_f(a0 * inv + b0.x);
        float r1 = selu_f(a1 * inv + b0.y);
        float r2 = selu_f(a2 * inv + b0.z);
        float r3 = selu_f(a3 * inv + b0.w);
        float r4 = selu_f(a4 * inv + b1.x);
        float r5 = selu_f(a5 * inv + b1.y);
        float r6 = selu_f(a6 * inv + b1.z);
        float r7 = selu_f(a7 * inv + b1.w);
        uint4 o;
        o.x = (uint32)f2bf(r0) | ((uint32)f2bf(r1) << 16);
        o.y = (uint32)f2bf(r2) | ((uint32)f2bf(r3) << 16);
        o.z = (uint32)f2bf(r4) | ((uint32)f2bf(r5) << 16);
        o.w = (uint32)f2bf(r6) | ((uint32)f2bf(r7) << 16);
        outb4[(uint32)node * 16u + fl] = o;
    }
}

// ------------- fused mean-pool + head, one block per graph ----------------
__global__ __launch_bounds__(128) void pool_head(const uint32* __restrict__ act,
                                                 const int* __restrict__ gstart,
                                                 const float* __restrict__ Wfc1,
                                                 const float* __restrict__ bfc1,
                                                 const float* __restrict__ Wfc2,
                                                 const float* __restrict__ bfc2,
                                                 float* __restrict__ out) {
    __shared__ float part[128][2];
    __shared__ float p[128];
    __shared__ float q[64];
    __shared__ float l[10];
    __shared__ float red[2];
    int g = blockIdx.x, t = threadIdx.x;
    int lo = gstart[g], hi = gstart[g + 1];
    int half = t >> 6, u = t & 63;
    float acc0 = 0.f, acc1 = 0.f;
    for (int nd = lo + half; nd < hi; nd += 2) {
        uint32 gv = act[(uint32)nd * 64u + u];
        acc0 += bf_lo(gv); acc1 += bf_hi(gv);
    }
    part[t][0] = acc0; part[t][1] = acc1;
    __syncthreads();
    if (half == 0) {
        float c = fmaxf((float)(hi - lo), 1.0f);
        p[2 * u]     = selu_f((acc0 + part[t + 64][0]) / c);
        p[2 * u + 1] = selu_f((acc1 + part[t + 64][1]) / c);
    }
    __syncthreads();
    if (t < 64) {
        float a = bfc1[t];
        #pragma unroll 8
        for (int k = 0; k < 128; ++k) a += p[k] * Wfc1[k * 64 + t];
        q[t] = selu_f(a);
    }
    __syncthreads();
    if (t < 10) {
        float a = bfc2[t];
        #pragma unroll
        for (int k = 0; k < 64; ++k) a += q[k] * Wfc2[k * 10 + t];
        l[t] = a;
    }
    __syncthreads();
    if (t == 0) {
        float mx = l[0];
        for (int c = 1; c < 10; ++c) mx = fmaxf(mx, l[c]);
        float sum = 0.0f;
        for (int c = 0; c < 10; ++c) sum += __expf(l[c] - mx);
        red[0] = mx; red[1] = logf(sum);
    }
    __syncthreads();
    if (t < 10) out[g * 10 + t] = l[t] - red[0] - red[1];
}

extern "C" void kernel_launch(void* const* d_in, const int* in_sizes, int n_in,
                              void* d_out, int out_size, void* d_ws, size_t ws_size,
                              hipStream_t stream) {
    const float* x      = (const float*)d_in[0];
    const int*   ei     = (const int*)d_in[1];
    const int*   batch  = (const int*)d_in[2];
    const float* W1     = (const float*)d_in[3];
    const float* asrc1  = (const float*)d_in[4];
    const float* adst1  = (const float*)d_in[5];
    const float* b1     = (const float*)d_in[6];
    const float* W2     = (const float*)d_in[7];
    const float* asrc2  = (const float*)d_in[8];
    const float* adst2  = (const float*)d_in[9];
    const float* b2     = (const float*)d_in[10];
    const float* Wfc1   = (const float*)d_in[11];
    const float* bfc1   = (const float*)d_in[12];
    const float* Wfc2   = (const float*)d_in[13];
    const float* bfc2   = (const float*)d_in[14];
    float* out = (float*)d_out;

    const int N = in_sizes[0] / 128;
    const int E = in_sizes[1] / 2;
    const int G = out_size / 10;
    const int TOT = E + N;
    const int NB = ((N - 1) >> BSHIFT) + 1;
    const int GB = (N + 255) / 256;
    const int PH = (TOT + PCHUNK - 1) / PCHUNK;

    // workspace layout
    uint32* hb    = (uint32*)d_ws;                   // N*64  (bf16 h, gather buf)
    uint32* h2b   = hb + (size_t)N * 64;             // N*64  (bf16 layer outputs)
    uint32* tmp   = h2b + (size_t)N * 64;            // TOT
    float* as_    = (float*)(tmp + TOT);             // N
    float* ad_    = as_ + N;                         // N
    int*   gstart = (int*)(ad_ + N);                 // G+1
    int*   rowptr = gstart + (G + 2);                // N+1
    int*   bstart = rowptr + (N + 2);                // MAXB+1
    int*   gcursor= bstart + MAXB + 1;               // MAXB
    int*   gpart  = gcursor + MAXB;                  // PH*MAXB
    int*   col    = gpart + PH * MAXB;               // TOT
    unsigned short* Wb = (unsigned short*)(((uintptr_t)(col + TOT) + 255) & ~(uintptr_t)255);

    const int gemmGrid = (N + 127) / 128;
    const int gatGrid  = (N + 3) / 4;

    // ---------------- prep (repack + graph bounds + hist) + CSR ----------
    prep<<<2 + GB + PH, 256, 0, stream>>>(W1, W2, Wb, batch, gstart, ei, gpart, N, G, E, TOT, GB);
    bucket_scan2<<<1, 256, 0, stream>>>(gpart, PH, bstart, gcursor, NB, TOT);
    partition_edges<<<PH, 256, 0, stream>>>(ei, gcursor, tmp, E, TOT);
    bucket_build<<<NB, 256, 0, stream>>>(tmp, bstart, rowptr, col, N, TOT, NB);

    // ---------------- layer 1 ----------------
    gemm_mfma_f32<<<gemmGrid, 256, 0, stream>>>(x, Wb, asrc1, adst1, hb, as_, ad_, N);
    gat_csr4<<<gatGrid, 256, 0, stream>>>(rowptr, col, (const uint4*)hb, as_, ad_, b1, (uint4*)h2b, N);

    // ---------------- layer 2 ----------------
    gemm_mfma_bf16<<<gemmGrid, 256, 0, stream>>>((const __bf16*)h2b, Wb + 32768, asrc2, adst2, hb, as_, ad_, N);
    gat_csr4<<<gatGrid, 256, 0, stream>>>(rowptr, col, (const uint4*)hb, as_, ad_, b2, (uint4*)h2b, N);

    // ---------------- pool + head ----------------
    pool_head<<<G, 128, 0, stream>>>(h2b, gstart, Wfc1, bfc1, Wfc2, bfc2, out);
}